// Round 1
// baseline (1008.176 us; speedup 1.0000x reference)
//
#include <hip/hip_runtime.h>
#include <math.h>

#define HWSZ 4096
#define W_ 64
#define H_ 64
#define C_ 256
#define B_ 8

// workspace layout (float offsets)
#define OFF_WS    0          // 8*18*4096 = 589824
#define MOD_WS    589824     // 8*9*4096  = 294912
#define M_WS      884736     // 8*256*4096 = 8388608
#define WT_WS     9273344    // 9*256*256 = 589824  (wt[kk][c][o])
#define WMT_WS    9863168    // 256*256   = 65536   (wmt[c][o])
#define SMEAN_WS  9928704    // 2048
#define SSCALE_WS 9930752    // 2048

// ---------------- k0: weight transposes ----------------
__global__ __launch_bounds__(256) void k0_transpose(
    const float* __restrict__ w_reg, const float* __restrict__ w_mask,
    float* __restrict__ ws) {
  int i = blockIdx.x * 256 + threadIdx.x;
  const int total = 589824 + 65536;
  if (i >= total) return;
  if (i < 589824) {
    int o = i & 255, c = (i >> 8) & 255, kk = i >> 16;
    ws[WT_WS + i] = w_reg[(o * C_ + c) * 9 + kk];
  } else {
    int e = i - 589824;
    int o = e & 255, c = e >> 8;
    ws[WMT_WS + e] = w_mask[o * C_ + c];
  }
}

// ---------------- k1: offset + modulator 3x3 convs ----------------
// one block per (b,h) row; 256 threads = 64 cols x 4 oc-groups of 7 channels
__global__ __launch_bounds__(256) void k1_offmod(
    const float* __restrict__ x, const float* __restrict__ w_off,
    const float* __restrict__ b_off, const float* __restrict__ w_mod,
    const float* __restrict__ b_mod, float* __restrict__ ws) {
  __shared__ float xs[16 * 3 * 66];       // 16 ch x 3 rows x 66 cols (zero-padded)
  __shared__ float wsh[16 * 9 * 4 * 8];   // [cl][tap][og][8] (7 oc + pad)
  int bid = blockIdx.x;
  int b = bid >> 6, h = bid & 63;
  int t = threadIdx.x;
  int n = t & 63, og = t >> 6;
  const float* xb = x + b * C_ * HWSZ;
  float4 a0 = make_float4(0, 0, 0, 0), a1 = make_float4(0, 0, 0, 0);

  for (int cc = 0; cc < C_; cc += 16) {
    __syncthreads();
    // stage weights: 4608 elements
    for (int e = t; e < 4608; e += 256) {
      int j = e & 7, g = (e >> 3) & 3, tap = (e >> 5) % 9, cl = e / 288;
      int oc = g * 7 + j;
      float v = 0.f;
      if (j < 7 && oc < 27) {
        if (oc < 18) v = w_off[(oc * C_ + cc + cl) * 9 + tap];
        else         v = w_mod[((oc - 18) * C_ + cc + cl) * 9 + tap];
      }
      wsh[e] = v;
    }
    // stage x: 16 ch x 3 rows x 66 cols = 3168
    for (int e = t; e < 3168; e += 256) {
      int col = e % 66, row = (e / 66) % 3, cl = e / 198;
      int y = h - 1 + row, xc = col - 1;
      float v = 0.f;
      if ((unsigned)y < 64u && (unsigned)xc < 64u)
        v = xb[(cc + cl) * HWSZ + y * W_ + xc];
      xs[e] = v;
    }
    __syncthreads();
    for (int cl = 0; cl < 16; cl++) {
      #pragma unroll
      for (int tap = 0; tap < 9; tap++) {
        int dy = tap / 3, dx = tap % 3;
        float xv = xs[(cl * 3 + dy) * 66 + n + dx];
        const float4* wp = (const float4*)&wsh[((cl * 9 + tap) * 4 + og) * 8];
        float4 w0 = wp[0], w1 = wp[1];
        a0.x = fmaf(xv, w0.x, a0.x); a0.y = fmaf(xv, w0.y, a0.y);
        a0.z = fmaf(xv, w0.z, a0.z); a0.w = fmaf(xv, w0.w, a0.w);
        a1.x = fmaf(xv, w1.x, a1.x); a1.y = fmaf(xv, w1.y, a1.y);
        a1.z = fmaf(xv, w1.z, a1.z); a1.w = fmaf(xv, w1.w, a1.w);
      }
    }
  }
  float av[8] = {a0.x, a0.y, a0.z, a0.w, a1.x, a1.y, a1.z, a1.w};
  #pragma unroll
  for (int j = 0; j < 7; j++) {
    int oc = og * 7 + j;
    if (oc < 18) {
      ws[OFF_WS + ((b * 18 + oc) * H_ + h) * W_ + n] = av[j] + b_off[oc];
    } else if (oc < 27) {
      float v = av[j] + b_mod[oc - 18];
      ws[MOD_WS + ((b * 9 + (oc - 18)) * H_ + h) * W_ + n] = 2.f / (1.f + expf(-v));
    }
  }
}

// ---------------- k2: deformable conv (+ fused mask 1x1 as tap 10) ----------------
__device__ __forceinline__ void gemm_accum(const float* __restrict__ wrow,
                                           const float* vbuf, int nb,
                                           float4* accA, float4* accB) {
  for (int c = 0; c < C_; c++) {
    const float4 va = *(const float4*)&vbuf[c * 64 + nb];
    const float4 vb = *(const float4*)&vbuf[c * 64 + nb + 4];
    const float4 wa = *(const float4*)&wrow[c * 256];
    const float4 wb = *(const float4*)&wrow[c * 256 + 4];
    const float wv[8] = {wa.x, wa.y, wa.z, wa.w, wb.x, wb.y, wb.z, wb.w};
    #pragma unroll
    for (int oi = 0; oi < 8; oi++) {
      accA[oi].x = fmaf(wv[oi], va.x, accA[oi].x);
      accA[oi].y = fmaf(wv[oi], va.y, accA[oi].y);
      accA[oi].z = fmaf(wv[oi], va.z, accA[oi].z);
      accA[oi].w = fmaf(wv[oi], va.w, accA[oi].w);
      accB[oi].x = fmaf(wv[oi], vb.x, accB[oi].x);
      accB[oi].y = fmaf(wv[oi], vb.y, accB[oi].y);
      accB[oi].z = fmaf(wv[oi], vb.z, accB[oi].z);
      accB[oi].w = fmaf(wv[oi], vb.w, accB[oi].w);
    }
  }
}

__global__ __launch_bounds__(256) void k2_deform(
    const float* __restrict__ x, const float* __restrict__ b_reg,
    const float* __restrict__ b_mask, float* ws, float* out) {
  __shared__ float vbuf[C_ * 64];   // 64 KB
  __shared__ int   midx[4 * 64];
  __shared__ float mwgt[4 * 64];
  int bid = blockIdx.x;
  int b = bid >> 6, h = bid & 63;
  int t = threadIdx.x;
  int n = t & 63, cg = t >> 6;
  int og = t >> 3, ng = t & 7;
  int ob = og << 3, nb = ng << 3;
  const float* xb = x + b * C_ * HWSZ;
  const float* wt = ws + WT_WS;
  float4 accA[8], accB[8];
  #pragma unroll
  for (int j = 0; j < 8; j++) {
    accA[j] = make_float4(0, 0, 0, 0);
    accB[j] = make_float4(0, 0, 0, 0);
  }

  for (int kk = 0; kk < 9; kk++) {
    __syncthreads();
    if (t < 64) {
      float dy = ws[OFF_WS + ((b * 18 + 2 * kk) * H_ + h) * W_ + t];
      float dx = ws[OFF_WS + ((b * 18 + 2 * kk + 1) * H_ + h) * W_ + t];
      float md = ws[MOD_WS + ((b * 9 + kk) * H_ + h) * W_ + t];
      float py = (float)(h + kk / 3 - 1) + dy;
      float px = (float)(t + kk % 3 - 1) + dx;
      float fy = floorf(py), fx = floorf(px);
      float ly = py - fy, lx = px - fx;
      int y0 = (int)fy, x0 = (int)fx;
      int y1 = y0 + 1, x1 = x0 + 1;
      float vy0 = ((unsigned)y0 < 64u) ? 1.f : 0.f;
      float vy1 = ((unsigned)y1 < 64u) ? 1.f : 0.f;
      float vx0 = ((unsigned)x0 < 64u) ? 1.f : 0.f;
      float vx1 = ((unsigned)x1 < 64u) ? 1.f : 0.f;
      int cy0 = min(max(y0, 0), 63), cy1 = min(max(y1, 0), 63);
      int cx0 = min(max(x0, 0), 63), cx1 = min(max(x1, 0), 63);
      midx[t]       = cy0 * W_ + cx0;
      midx[64 + t]  = cy0 * W_ + cx1;
      midx[128 + t] = cy1 * W_ + cx0;
      midx[192 + t] = cy1 * W_ + cx1;
      mwgt[t]       = (1.f - ly) * (1.f - lx) * md * vy0 * vx0;
      mwgt[64 + t]  = (1.f - ly) * lx * md * vy0 * vx1;
      mwgt[128 + t] = ly * (1.f - lx) * md * vy1 * vx0;
      mwgt[192 + t] = ly * lx * md * vy1 * vx1;
    }
    __syncthreads();
    {
      int i00 = midx[n], i01 = midx[64 + n], i10 = midx[128 + n], i11 = midx[192 + n];
      float w00 = mwgt[n], w01 = mwgt[64 + n], w10 = mwgt[128 + n], w11 = mwgt[192 + n];
      for (int i = 0; i < 64; i++) {
        int c = cg + (i << 2);
        const float* xc = xb + c * HWSZ;
        vbuf[c * 64 + n] = w00 * xc[i00] + w01 * xc[i01] + w10 * xc[i10] + w11 * xc[i11];
      }
    }
    __syncthreads();
    gemm_accum(wt + kk * 65536 + ob, vbuf, nb, accA, accB);
  }
  // epilogue: write f to out, reset acc
  #pragma unroll
  for (int oi = 0; oi < 8; oi++) {
    int o = ob + oi;
    float bo = b_reg[o];
    float* op = out + ((b * C_ + o) * H_ + h) * W_ + nb;
    float4 fa = accA[oi], fb = accB[oi];
    fa.x += bo; fa.y += bo; fa.z += bo; fa.w += bo;
    fb.x += bo; fb.y += bo; fb.z += bo; fb.w += bo;
    *(float4*)op = fa;
    *(float4*)(op + 4) = fb;
    accA[oi] = make_float4(0, 0, 0, 0);
    accB[oi] = make_float4(0, 0, 0, 0);
  }
  // mask tap: plain x, 1x1 conv, hardsigmoid
  __syncthreads();
  for (int i = 0; i < 64; i++) {
    int c = cg + (i << 2);
    vbuf[c * 64 + n] = xb[c * HWSZ + h * W_ + n];
  }
  __syncthreads();
  gemm_accum(ws + WMT_WS + ob, vbuf, nb, accA, accB);
  #pragma unroll
  for (int oi = 0; oi < 8; oi++) {
    int o = ob + oi;
    float bm = b_mask[o];
    float* mp = ws + M_WS + ((b * C_ + o) * H_ + h) * W_ + nb;
    float4 ma = accA[oi], mb = accB[oi];
    ma.x = fminf(fmaxf((ma.x + bm) * (1.f / 6.f) + 0.5f, 0.f), 1.f);
    ma.y = fminf(fmaxf((ma.y + bm) * (1.f / 6.f) + 0.5f, 0.f), 1.f);
    ma.z = fminf(fmaxf((ma.z + bm) * (1.f / 6.f) + 0.5f, 0.f), 1.f);
    ma.w = fminf(fmaxf((ma.w + bm) * (1.f / 6.f) + 0.5f, 0.f), 1.f);
    mb.x = fminf(fmaxf((mb.x + bm) * (1.f / 6.f) + 0.5f, 0.f), 1.f);
    mb.y = fminf(fmaxf((mb.y + bm) * (1.f / 6.f) + 0.5f, 0.f), 1.f);
    mb.z = fminf(fmaxf((mb.z + bm) * (1.f / 6.f) + 0.5f, 0.f), 1.f);
    mb.w = fminf(fmaxf((mb.w + bm) * (1.f / 6.f) + 0.5f, 0.f), 1.f);
    *(float4*)mp = ma;
    *(float4*)(mp + 4) = mb;
  }
}

// ---------------- k3: SE global mean ----------------
__global__ __launch_bounds__(256) void k3_reduce(const float* __restrict__ f,
                                                 float* __restrict__ ws) {
  int bc = blockIdx.x;  // b*256 + c
  int t = threadIdx.x;
  const float* fp = f + (size_t)bc * HWSZ;
  float s = 0.f;
  #pragma unroll
  for (int j = 0; j < 4; j++) {
    float4 v = *(const float4*)&fp[(j * 256 + t) * 4];
    s += v.x + v.y + v.z + v.w;
  }
  #pragma unroll
  for (int off = 32; off > 0; off >>= 1) s += __shfl_down(s, off, 64);
  __shared__ float ps[4];
  if ((t & 63) == 0) ps[t >> 6] = s;
  __syncthreads();
  if (t == 0) ws[SMEAN_WS + bc] = (ps[0] + ps[1] + ps[2] + ps[3]) * (1.f / HWSZ);
}

// ---------------- k4: SE MLP ----------------
__global__ __launch_bounds__(256) void k4_se(
    const float* __restrict__ w_se1, const float* __restrict__ b_se1,
    const float* __restrict__ w_se2, const float* __restrict__ b_se2,
    float* __restrict__ ws) {
  __shared__ float sm[2048];
  __shared__ float s1[512];
  int t = threadIdx.x;
  for (int e = t; e < 2048; e += 256) sm[e] = ws[SMEAN_WS + e];
  __syncthreads();
  for (int e = t; e < 512; e += 256) {
    int b = e >> 6, cr = e & 63;
    float a = b_se1[cr];
    for (int c = 0; c < 256; c++) a += sm[b * 256 + c] * w_se1[cr * 256 + c];
    s1[e] = fmaxf(a, 0.f);
  }
  __syncthreads();
  for (int e = t; e < 2048; e += 256) {
    int b = e >> 8, c = e & 255;
    float a = b_se2[c];
    for (int cr = 0; cr < 64; cr++) a += s1[b * 64 + cr] * w_se2[c * 64 + cr];
    ws[SSCALE_WS + e] = 1.f / (1.f + expf(-a));
  }
}

// ---------------- k5: final combine ----------------
__global__ __launch_bounds__(256) void k5_final(const float* __restrict__ x,
                                                const float* __restrict__ ws,
                                                float* out) {
  int i4 = blockIdx.x * 256 + threadIdx.x;
  const int total = B_ * C_ * HWSZ / 4;
  for (; i4 < total; i4 += gridDim.x * 256) {
    int i = i4 * 4;
    int bc = i / HWSZ;
    float s = ws[SSCALE_WS + bc];
    float4 f = *(const float4*)&out[i];
    float4 m = *(const float4*)&ws[M_WS + i];
    float4 xv = *(const float4*)&x[i];
    float4 r;
    r.x = f.x * s * m.x + xv.x;
    r.y = f.y * s * m.y + xv.y;
    r.z = f.z * s * m.z + xv.z;
    r.w = f.w * s * m.w + xv.w;
    *(float4*)&out[i] = r;
  }
}

extern "C" void kernel_launch(void* const* d_in, const int* in_sizes, int n_in,
                              void* d_out, int out_size, void* d_ws, size_t ws_size,
                              hipStream_t stream) {
  const float* x      = (const float*)d_in[0];
  const float* w_off  = (const float*)d_in[1];
  const float* b_off  = (const float*)d_in[2];
  const float* w_mod  = (const float*)d_in[3];
  const float* b_mod  = (const float*)d_in[4];
  const float* w_reg  = (const float*)d_in[5];
  const float* b_reg  = (const float*)d_in[6];
  const float* w_se1  = (const float*)d_in[7];
  const float* b_se1  = (const float*)d_in[8];
  const float* w_se2  = (const float*)d_in[9];
  const float* b_se2  = (const float*)d_in[10];
  const float* w_mask = (const float*)d_in[11];
  const float* b_mask = (const float*)d_in[12];
  float* out = (float*)d_out;
  float* ws  = (float*)d_ws;

  k0_transpose<<<dim3(2560), dim3(256), 0, stream>>>(w_reg, w_mask, ws);
  k1_offmod<<<dim3(512), dim3(256), 0, stream>>>(x, w_off, b_off, w_mod, b_mod, ws);
  k2_deform<<<dim3(512), dim3(256), 0, stream>>>(x, b_reg, b_mask, ws, out);
  k3_reduce<<<dim3(2048), dim3(256), 0, stream>>>(out, ws);
  k4_se<<<dim3(1), dim3(256), 0, stream>>>(w_se1, b_se1, w_se2, b_se2, ws);
  k5_final<<<dim3(2048), dim3(256), 0, stream>>>(x, ws, out);
}

// Round 2
// 535.122 us; speedup vs baseline: 1.8840x; 1.8840x over previous
//
#include <hip/hip_runtime.h>
#include <math.h>

#define HWSZ 4096
#define W_ 64
#define H_ 64
#define C_ 256
#define B_ 8

// workspace layout (float offsets)
#define OFF_WS    0          // 8*18*4096 = 589824
#define MOD_WS    589824     // 8*9*4096  = 294912
#define M_WS      884736     // 8*256*4096 = 8388608
#define WT2_WS    9273344    // 10*256*256 bf16 = 655360 ushort = 327680 floats
#define SMEAN_WS  9601024    // 2048
#define SSCALE_WS 9603072    // 2048

typedef __attribute__((ext_vector_type(8))) short short8;
typedef __attribute__((ext_vector_type(4))) float f32x4;

__device__ __forceinline__ uint pk2(float a, float b) {
  uint ua = __float_as_uint(a); ua = (ua + 0x7fffu + ((ua >> 16) & 1u)) >> 16;
  uint ub = __float_as_uint(b); ub = (ub + 0x7fffu + ((ub >> 16) & 1u)) >> 16;
  return ua | (ub << 16);
}

// ---------------- k0: weight transpose + bf16 cast ----------------
// wt2[kk][o][c] bf16, kk=0..8 from w_reg, kk=9 from w_mask
__global__ __launch_bounds__(256) void k0_transpose(
    const float* __restrict__ w_reg, const float* __restrict__ w_mask,
    float* __restrict__ ws) {
  int i = blockIdx.x * 256 + threadIdx.x;
  const int total = 10 * 256 * 256;
  if (i >= total) return;
  ushort* wt2 = (ushort*)(ws + WT2_WS);
  float v;
  if (i < 9 * 65536) {
    int kk = i >> 16, o = (i >> 8) & 255, c = i & 255;
    v = w_reg[(o * C_ + c) * 9 + kk];
  } else {
    int e = i - 9 * 65536;
    int o = e >> 8, c = e & 255;
    v = w_mask[o * C_ + c];
  }
  uint u = __float_as_uint(v);
  wt2[i] = (ushort)((u + 0x7fffu + ((u >> 16) & 1u)) >> 16);
}

// ---------------- k1: offset + modulator 3x3 convs (fp32) ----------------
__global__ __launch_bounds__(256) void k1_offmod(
    const float* __restrict__ x, const float* __restrict__ w_off,
    const float* __restrict__ b_off, const float* __restrict__ w_mod,
    const float* __restrict__ b_mod, float* __restrict__ ws) {
  __shared__ float xs[16 * 3 * 66];
  __shared__ float wsh[16 * 9 * 4 * 8];
  int bid = blockIdx.x;
  int b = bid >> 6, h = bid & 63;
  int t = threadIdx.x;
  int n = t & 63, og = t >> 6;
  const float* xb = x + b * C_ * HWSZ;
  float4 a0 = make_float4(0, 0, 0, 0), a1 = make_float4(0, 0, 0, 0);

  for (int cc = 0; cc < C_; cc += 16) {
    __syncthreads();
    for (int e = t; e < 4608; e += 256) {
      int j = e & 7, g = (e >> 3) & 3, tap = (e >> 5) % 9, cl = e / 288;
      int oc = g * 7 + j;
      float v = 0.f;
      if (j < 7 && oc < 27) {
        if (oc < 18) v = w_off[(oc * C_ + cc + cl) * 9 + tap];
        else         v = w_mod[((oc - 18) * C_ + cc + cl) * 9 + tap];
      }
      wsh[e] = v;
    }
    for (int e = t; e < 3168; e += 256) {
      int col = e % 66, row = (e / 66) % 3, cl = e / 198;
      int y = h - 1 + row, xc = col - 1;
      float v = 0.f;
      if ((unsigned)y < 64u && (unsigned)xc < 64u)
        v = xb[(cc + cl) * HWSZ + y * W_ + xc];
      xs[e] = v;
    }
    __syncthreads();
    for (int cl = 0; cl < 16; cl++) {
      #pragma unroll
      for (int tap = 0; tap < 9; tap++) {
        int dy = tap / 3, dx = tap % 3;
        float xv = xs[(cl * 3 + dy) * 66 + n + dx];
        const float4* wp = (const float4*)&wsh[((cl * 9 + tap) * 4 + og) * 8];
        float4 w0 = wp[0], w1 = wp[1];
        a0.x = fmaf(xv, w0.x, a0.x); a0.y = fmaf(xv, w0.y, a0.y);
        a0.z = fmaf(xv, w0.z, a0.z); a0.w = fmaf(xv, w0.w, a0.w);
        a1.x = fmaf(xv, w1.x, a1.x); a1.y = fmaf(xv, w1.y, a1.y);
        a1.z = fmaf(xv, w1.z, a1.z); a1.w = fmaf(xv, w1.w, a1.w);
      }
    }
  }
  float av[8] = {a0.x, a0.y, a0.z, a0.w, a1.x, a1.y, a1.z, a1.w};
  #pragma unroll
  for (int j = 0; j < 7; j++) {
    int oc = og * 7 + j;
    if (oc < 18) {
      ws[OFF_WS + ((b * 18 + oc) * H_ + h) * W_ + n] = av[j] + b_off[oc];
    } else if (oc < 27) {
      float v = av[j] + b_mod[oc - 18];
      ws[MOD_WS + ((b * 9 + (oc - 18)) * H_ + h) * W_ + n] = 2.f / (1.f + expf(-v));
    }
  }
}

// ---------------- k2: deformable conv via bf16 MFMA (+ fused mask tap) ----------------
// block = one (b,h) row: output 256 o x 64 n. 4 waves, wave wv owns o in [wv*64, wv*64+64).
// V staged in LDS as [n][c] bf16 with slot ^= (n&7) XOR swizzle (16B slots).
__global__ __launch_bounds__(256, 2) void k2_deform(
    const float* __restrict__ x, const float* __restrict__ b_reg,
    const float* __restrict__ b_mask, float* __restrict__ ws,
    float* __restrict__ out) {
  __shared__ uint vbuf32[64 * 128];   // 32 KB: [n][128 uints], swizzled
  __shared__ int   midx[256];
  __shared__ float mwgt[256];
  int bid = blockIdx.x;
  int b = bid >> 6, h = bid & 63;
  int t = threadIdx.x;
  int lane = t & 63;
  int wv = t >> 6;
  int n = lane;           // gather: position
  int cbase = wv * 64;    // gather: channel range
  int o0 = wv * 64;       // gemm: o range
  const float* xb = x + b * C_ * HWSZ;
  const ushort* wt2 = (const ushort*)(ws + WT2_WS);
  f32x4 acc[4][4];
  #pragma unroll
  for (int m = 0; m < 4; m++)
    #pragma unroll
    for (int nt = 0; nt < 4; nt++) acc[m][nt] = (f32x4)0.f;

  const uint rowu = (uint)n * 128u;
  const uint sw = (uint)(n & 7) << 2;
  const int fr = lane & 15;   // tile row (A: o, B: n)
  const int fq = lane >> 4;   // K-chunk selector

  for (int kk = 0; kk < 9; kk++) {
    __syncthreads();
    if (t < 64) {
      float dy = ws[OFF_WS + ((b * 18 + 2 * kk) * H_ + h) * W_ + t];
      float dx = ws[OFF_WS + ((b * 18 + 2 * kk + 1) * H_ + h) * W_ + t];
      float md = ws[MOD_WS + ((b * 9 + kk) * H_ + h) * W_ + t];
      float py = (float)(h + kk / 3 - 1) + dy;
      float px = (float)(t + kk % 3 - 1) + dx;
      float fy = floorf(py), fx = floorf(px);
      float ly = py - fy, lx = px - fx;
      int y0 = (int)fy, x0 = (int)fx;
      int y1 = y0 + 1, x1 = x0 + 1;
      float vy0 = ((unsigned)y0 < 64u) ? 1.f : 0.f;
      float vy1 = ((unsigned)y1 < 64u) ? 1.f : 0.f;
      float vx0 = ((unsigned)x0 < 64u) ? 1.f : 0.f;
      float vx1 = ((unsigned)x1 < 64u) ? 1.f : 0.f;
      int cy0 = min(max(y0, 0), 63), cy1 = min(max(y1, 0), 63);
      int cx0 = min(max(x0, 0), 63), cx1 = min(max(x1, 0), 63);
      midx[t]       = cy0 * W_ + cx0;
      midx[64 + t]  = cy0 * W_ + cx1;
      midx[128 + t] = cy1 * W_ + cx0;
      midx[192 + t] = cy1 * W_ + cx1;
      mwgt[t]       = (1.f - ly) * (1.f - lx) * md * vy0 * vx0;
      mwgt[64 + t]  = (1.f - ly) * lx * md * vy0 * vx1;
      mwgt[128 + t] = ly * (1.f - lx) * md * vy1 * vx0;
      mwgt[192 + t] = ly * lx * md * vy1 * vx1;
    }
    __syncthreads();
    {
      int i00 = midx[n], i01 = midx[64 + n], i10 = midx[128 + n], i11 = midx[192 + n];
      float w00 = mwgt[n], w01 = mwgt[64 + n], w10 = mwgt[128 + n], w11 = mwgt[192 + n];
      #pragma unroll 2
      for (int i0 = 0; i0 < 64; i0 += 8) {
        float v[8];
        #pragma unroll
        for (int j = 0; j < 8; j++) {
          const float* xc = xb + (cbase + i0 + j) * HWSZ;
          v[j] = w00 * xc[i00] + w01 * xc[i01] + w10 * xc[i10] + w11 * xc[i11];
        }
        uint4 pkv = make_uint4(pk2(v[0], v[1]), pk2(v[2], v[3]),
                               pk2(v[4], v[5]), pk2(v[6], v[7]));
        *(uint4*)&vbuf32[rowu + (((uint)(cbase + i0) >> 1) ^ sw)] = pkv;
      }
    }
    __syncthreads();
    const ushort* wtap = wt2 + (size_t)kk * 65536;
    for (int ks = 0; ks < 8; ks++) {
      short8 af[4], bf[4];
      #pragma unroll
      for (int m = 0; m < 4; m++)
        af[m] = *(const short8*)(wtap + (o0 + m * 16 + fr) * 256 + ks * 32 + fq * 8);
      #pragma unroll
      for (int nt = 0; nt < 4; nt++) {
        int bn = nt * 16 + fr;
        uint idx = (uint)bn * 128u + ((uint)(ks * 16 + fq * 4) ^ ((uint)(bn & 7) << 2));
        bf[nt] = *(const short8*)&vbuf32[idx];
      }
      #pragma unroll
      for (int m = 0; m < 4; m++)
        #pragma unroll
        for (int nt = 0; nt < 4; nt++)
          acc[m][nt] = __builtin_amdgcn_mfma_f32_16x16x32_bf16(af[m], bf[nt], acc[m][nt], 0, 0, 0);
    }
  }
  // f epilogue: D[o][n]: o = o0 + m*16 + fq*4 + r, n = nt*16 + fr
  #pragma unroll
  for (int m = 0; m < 4; m++) {
    #pragma unroll
    for (int r = 0; r < 4; r++) {
      int o = o0 + m * 16 + fq * 4 + r;
      float bo = b_reg[o];
      float* op = out + (size_t)(b * C_ + o) * HWSZ + h * W_;
      #pragma unroll
      for (int nt = 0; nt < 4; nt++) {
        op[nt * 16 + fr] = acc[m][nt][r] + bo;
        acc[m][nt][r] = 0.f;
      }
    }
  }
  // mask tap: plain x row, 1x1 conv (tap 9), hardsigmoid
  __syncthreads();
  {
    const float* xr = xb + h * W_ + n;
    #pragma unroll 2
    for (int i0 = 0; i0 < 64; i0 += 8) {
      float v[8];
      #pragma unroll
      for (int j = 0; j < 8; j++) v[j] = xr[(cbase + i0 + j) * HWSZ];
      uint4 pkv = make_uint4(pk2(v[0], v[1]), pk2(v[2], v[3]),
                             pk2(v[4], v[5]), pk2(v[6], v[7]));
      *(uint4*)&vbuf32[rowu + (((uint)(cbase + i0) >> 1) ^ sw)] = pkv;
    }
  }
  __syncthreads();
  {
    const ushort* wtap = wt2 + (size_t)9 * 65536;
    for (int ks = 0; ks < 8; ks++) {
      short8 af[4], bf[4];
      #pragma unroll
      for (int m = 0; m < 4; m++)
        af[m] = *(const short8*)(wtap + (o0 + m * 16 + fr) * 256 + ks * 32 + fq * 8);
      #pragma unroll
      for (int nt = 0; nt < 4; nt++) {
        int bn = nt * 16 + fr;
        uint idx = (uint)bn * 128u + ((uint)(ks * 16 + fq * 4) ^ ((uint)(bn & 7) << 2));
        bf[nt] = *(const short8*)&vbuf32[idx];
      }
      #pragma unroll
      for (int m = 0; m < 4; m++)
        #pragma unroll
        for (int nt = 0; nt < 4; nt++)
          acc[m][nt] = __builtin_amdgcn_mfma_f32_16x16x32_bf16(af[m], bf[nt], acc[m][nt], 0, 0, 0);
    }
  }
  #pragma unroll
  for (int m = 0; m < 4; m++) {
    #pragma unroll
    for (int r = 0; r < 4; r++) {
      int o = o0 + m * 16 + fq * 4 + r;
      float bm = b_mask[o];
      float* mp = ws + M_WS + (size_t)(b * C_ + o) * HWSZ + h * W_;
      #pragma unroll
      for (int nt = 0; nt < 4; nt++) {
        float mv = (acc[m][nt][r] + bm) * (1.f / 6.f) + 0.5f;
        mp[nt * 16 + fr] = fminf(fmaxf(mv, 0.f), 1.f);
      }
    }
  }
}

// ---------------- k3: SE global mean ----------------
__global__ __launch_bounds__(256) void k3_reduce(const float* __restrict__ f,
                                                 float* __restrict__ ws) {
  int bc = blockIdx.x;
  int t = threadIdx.x;
  const float* fp = f + (size_t)bc * HWSZ;
  float s = 0.f;
  #pragma unroll
  for (int j = 0; j < 4; j++) {
    float4 v = *(const float4*)&fp[(j * 256 + t) * 4];
    s += v.x + v.y + v.z + v.w;
  }
  #pragma unroll
  for (int off = 32; off > 0; off >>= 1) s += __shfl_down(s, off, 64);
  __shared__ float ps[4];
  if ((t & 63) == 0) ps[t >> 6] = s;
  __syncthreads();
  if (t == 0) ws[SMEAN_WS + bc] = (ps[0] + ps[1] + ps[2] + ps[3]) * (1.f / HWSZ);
}

// ---------------- k4: SE MLP ----------------
__global__ __launch_bounds__(256) void k4_se(
    const float* __restrict__ w_se1, const float* __restrict__ b_se1,
    const float* __restrict__ w_se2, const float* __restrict__ b_se2,
    float* __restrict__ ws) {
  __shared__ float sm[2048];
  __shared__ float s1[512];
  int t = threadIdx.x;
  for (int e = t; e < 2048; e += 256) sm[e] = ws[SMEAN_WS + e];
  __syncthreads();
  for (int e = t; e < 512; e += 256) {
    int b = e >> 6, cr = e & 63;
    float a = b_se1[cr];
    for (int c = 0; c < 256; c++) a += sm[b * 256 + c] * w_se1[cr * 256 + c];
    s1[e] = fmaxf(a, 0.f);
  }
  __syncthreads();
  for (int e = t; e < 2048; e += 256) {
    int b = e >> 8, c = e & 255;
    float a = b_se2[c];
    for (int cr = 0; cr < 64; cr++) a += s1[b * 64 + cr] * w_se2[c * 64 + cr];
    ws[SSCALE_WS + e] = 1.f / (1.f + expf(-a));
  }
}

// ---------------- k5: final combine ----------------
__global__ __launch_bounds__(256) void k5_final(const float* __restrict__ x,
                                                const float* __restrict__ ws,
                                                float* __restrict__ out) {
  int i4 = blockIdx.x * 256 + threadIdx.x;
  const int total = B_ * C_ * HWSZ / 4;
  for (; i4 < total; i4 += gridDim.x * 256) {
    int i = i4 * 4;
    int bc = i / HWSZ;
    float s = ws[SSCALE_WS + bc];
    float4 f = *(const float4*)&out[i];
    float4 m = *(const float4*)&ws[M_WS + i];
    float4 xv = *(const float4*)&x[i];
    float4 r;
    r.x = f.x * s * m.x + xv.x;
    r.y = f.y * s * m.y + xv.y;
    r.z = f.z * s * m.z + xv.z;
    r.w = f.w * s * m.w + xv.w;
    *(float4*)&out[i] = r;
  }
}

extern "C" void kernel_launch(void* const* d_in, const int* in_sizes, int n_in,
                              void* d_out, int out_size, void* d_ws, size_t ws_size,
                              hipStream_t stream) {
  const float* x      = (const float*)d_in[0];
  const float* w_off  = (const float*)d_in[1];
  const float* b_off  = (const float*)d_in[2];
  const float* w_mod  = (const float*)d_in[3];
  const float* b_mod  = (const float*)d_in[4];
  const float* w_reg  = (const float*)d_in[5];
  const float* b_reg  = (const float*)d_in[6];
  const float* w_se1  = (const float*)d_in[7];
  const float* b_se1  = (const float*)d_in[8];
  const float* w_se2  = (const float*)d_in[9];
  const float* b_se2  = (const float*)d_in[10];
  const float* w_mask = (const float*)d_in[11];
  const float* b_mask = (const float*)d_in[12];
  float* out = (float*)d_out;
  float* ws  = (float*)d_ws;

  k0_transpose<<<dim3(2560), dim3(256), 0, stream>>>(w_reg, w_mask, ws);
  k1_offmod<<<dim3(512), dim3(256), 0, stream>>>(x, w_off, b_off, w_mod, b_mod, ws);
  k2_deform<<<dim3(512), dim3(256), 0, stream>>>(x, b_reg, b_mask, ws, out);
  k3_reduce<<<dim3(2048), dim3(256), 0, stream>>>(out, ws);
  k4_se<<<dim3(1), dim3(256), 0, stream>>>(w_se1, b_se1, w_se2, b_se2, ws);
  k5_final<<<dim3(2048), dim3(256), 0, stream>>>(x, ws, out);
}

// Round 3
// 340.444 us; speedup vs baseline: 2.9614x; 1.5718x over previous
//
#include <hip/hip_runtime.h>
#include <math.h>

#define HWSZ 4096
#define C_ 256
#define B_ 8

// ws layout (float offsets)
#define M_WS      0          // mask bf16: 8*256*4096 ushort = 4194304 floats
#define XB_WS     4194304    // x bf16:    8*256*4096 ushort = 4194304 floats
#define WT2_WS    8388608    // 10*256*256 ushort = 327680 floats
#define WOM_WS    8716288    // 9*32*256 ushort   = 36864 floats
#define SMEAN_WS  8753152    // 2048
#define SSCALE_WS 8755200    // 2048  (end: 8757248 floats = 35.0 MB)

typedef __attribute__((ext_vector_type(8))) short short8;
typedef __attribute__((ext_vector_type(4))) float f32x4;

__device__ __forceinline__ uint bfr(float a) {  // f32 -> bf16 bits (RNE)
  uint u = __float_as_uint(a);
  return (u + 0x7fffu + ((u >> 16) & 1u)) >> 16;
}
__device__ __forceinline__ uint pk2(float a, float b) { return bfr(a) | (bfr(b) << 16); }
__device__ __forceinline__ float bff(ushort u) { return __uint_as_float((uint)u << 16); }

// ---------------- k0: weight transpose + bf16 cast ----------------
// wt2[kk 0..9][o][c] (kk=9 <- w_mask);  wom[s 0..8][o2 0..31][c] (o2<18 off, 18..26 mod, else 0)
__global__ __launch_bounds__(256) void k0_weights(
    const float* __restrict__ w_reg, const float* __restrict__ w_mask,
    const float* __restrict__ w_off, const float* __restrict__ w_mod,
    float* __restrict__ ws) {
  int i = blockIdx.x * 256 + threadIdx.x;
  const int nwt = 10 * 65536;
  const int total = nwt + 9 * 32 * 256;
  if (i >= total) return;
  float v;
  if (i < 9 * 65536) {
    int kk = i >> 16, o = (i >> 8) & 255, c = i & 255;
    v = w_reg[(o * C_ + c) * 9 + kk];
  } else if (i < nwt) {
    int e = i - 9 * 65536;
    v = w_mask[e];                       // [o][c] contiguous
  } else {
    int e = i - nwt;
    int s = e >> 13, r = e & 8191;
    int o2 = r >> 8, c = r & 255;
    if (o2 < 18)      v = w_off[(o2 * C_ + c) * 9 + s];
    else if (o2 < 27) v = w_mod[((o2 - 18) * C_ + c) * 9 + s];
    else              v = 0.f;
  }
  ((ushort*)(ws + WT2_WS))[i] = (ushort)bfr(v);
}

// ---------------- k0b: x -> bf16 ----------------
__global__ __launch_bounds__(256) void k0b_xcast(const float* __restrict__ x,
                                                 float* __restrict__ ws) {
  uint* xb = (uint*)(ws + XB_WS);
  const int total = B_ * C_ * HWSZ / 2;  // uints
  for (int i = blockIdx.x * 256 + threadIdx.x; i < total; i += gridDim.x * 256) {
    float2 v = *(const float2*)&x[(size_t)i * 2];
    xb[i] = pk2(v.x, v.y);
  }
}

// ---------------- k2: fused off/mod conv + deformable conv + mask (bf16 MFMA) ----------------
// block = 512 thr (8 waves) per (b,h). GEMM: wave w owns o in [w*32,w*32+32) x 64 n.
// Phase 0: 9-shift im2col conv -> off/mod (M=32xN=64, wave w = tile (m=w>>2, nt=w&3)).
__global__ __launch_bounds__(512, 4) void k2_fused(
    const float* __restrict__ b_off, const float* __restrict__ b_mod,
    const float* __restrict__ b_reg, const float* __restrict__ b_mask,
    float* __restrict__ ws, float* __restrict__ out) {
  __shared__ uint  vbuf32[64 * 128];   // 32 KB [n][128 uints] swizzled
  __shared__ float offmod[27 * 64];    // off rows 0..17, mod 18..26
  __shared__ int   midx[9 * 4 * 64];
  __shared__ float mwgt[9 * 4 * 64];

  int bl = ((blockIdx.x & 7) << 6) | (blockIdx.x >> 3);   // XCD k -> image k
  int b = bl >> 6, h = bl & 63;
  int t = threadIdx.x;
  int lane = t & 63, w = t >> 6;
  int n = lane, c0 = w << 5;           // staging: 32 channels per wave
  const ushort* xb2 = (const ushort*)(ws + XB_WS) + (size_t)b * C_ * HWSZ;
  const ushort* wt2 = (const ushort*)(ws + WT2_WS);
  const ushort* wom = wt2 + 10 * 65536;
  const uint rowu = (uint)n * 128u;
  const uint sw = (uint)(n & 7) << 2;
  const int fr = lane & 15, fq = lane >> 4;

  // ---- Phase 0: offset/modulator conv ----
  f32x4 aom = (f32x4)0.f;
  const int m0 = w >> 2, nt0 = w & 3;
  for (int s = 0; s < 9; s++) {
    int row = h + s / 3 - 1;
    int col = n + s % 3 - 1;
    uint pk[16];
    if (((unsigned)row < 64u) && ((unsigned)col < 64u)) {
      const ushort* xp = xb2 + row * 64 + col;
      #pragma unroll 4
      for (int j = 0; j < 16; j++) {
        uint lo = xp[(size_t)(c0 + 2 * j) * HWSZ];
        uint hi = xp[(size_t)(c0 + 2 * j + 1) * HWSZ];
        pk[j] = lo | (hi << 16);
      }
    } else {
      #pragma unroll
      for (int j = 0; j < 16; j++) pk[j] = 0;
    }
    __syncthreads();   // prev GEMM done reading vbuf
    #pragma unroll
    for (int k4 = 0; k4 < 4; k4++)
      *(uint4*)&vbuf32[rowu + ((((uint)(c0 >> 1)) + 4u * k4) ^ sw)] =
          make_uint4(pk[k4 * 4], pk[k4 * 4 + 1], pk[k4 * 4 + 2], pk[k4 * 4 + 3]);
    __syncthreads();
    const ushort* wp = wom + (size_t)s * 8192;
    for (int ks = 0; ks < 8; ks++) {
      short8 af = *(const short8*)(wp + (m0 * 16 + fr) * 256 + ks * 32 + fq * 8);
      int bn = nt0 * 16 + fr;
      uint idx = (uint)bn * 128u + (((uint)(ks * 16 + fq * 4)) ^ ((uint)(bn & 7) << 2));
      short8 bf = *(const short8*)&vbuf32[idx];
      aom = __builtin_amdgcn_mfma_f32_16x16x32_bf16(af, bf, aom, 0, 0, 0);
    }
  }
  __syncthreads();
  #pragma unroll
  for (int r = 0; r < 4; r++) {
    int o = m0 * 16 + fq * 4 + r;
    int nn = nt0 * 16 + fr;
    if (o < 18) {
      offmod[o * 64 + nn] = aom[r] + b_off[o];
    } else if (o < 27) {
      float v = aom[r] + b_mod[o - 18];
      offmod[o * 64 + nn] = 2.f / (1.f + expf(-v));
    }
  }
  __syncthreads();

  // ---- midx/mwgt for all 9 taps ----
  for (int e = t; e < 576; e += 512) {
    int kk = e >> 6, p = e & 63;
    float dy = offmod[(2 * kk) * 64 + p];
    float dx = offmod[(2 * kk + 1) * 64 + p];
    float md = offmod[(18 + kk) * 64 + p];
    float py = (float)(h + kk / 3 - 1) + dy;
    float px = (float)(p + kk % 3 - 1) + dx;
    float fy = floorf(py), fx = floorf(px);
    float ly = py - fy, lx = px - fx;
    int y0 = (int)fy, x0 = (int)fx;
    int y1 = y0 + 1, x1 = x0 + 1;
    float vy0 = ((unsigned)y0 < 64u) ? 1.f : 0.f;
    float vy1 = ((unsigned)y1 < 64u) ? 1.f : 0.f;
    float vx0 = ((unsigned)x0 < 64u) ? 1.f : 0.f;
    float vx1 = ((unsigned)x1 < 64u) ? 1.f : 0.f;
    int cy0 = min(max(y0, 0), 63), cy1 = min(max(y1, 0), 63);
    int cx0 = min(max(x0, 0), 63), cx1 = min(max(x1, 0), 63);
    int base = kk * 256 + p;
    midx[base]       = cy0 * 64 + cx0;
    midx[base + 64]  = cy0 * 64 + cx1;
    midx[base + 128] = cy1 * 64 + cx0;
    midx[base + 192] = cy1 * 64 + cx1;
    mwgt[base]       = (1.f - ly) * (1.f - lx) * md * vy0 * vx0;
    mwgt[base + 64]  = (1.f - ly) * lx * md * vy0 * vx1;
    mwgt[base + 128] = ly * (1.f - lx) * md * vy1 * vx0;
    mwgt[base + 192] = ly * lx * md * vy1 * vx1;
  }

  // ---- Phase 1: 9 deform taps ----
  f32x4 acc[2][4];
  #pragma unroll
  for (int mt = 0; mt < 2; mt++)
    #pragma unroll
    for (int nt = 0; nt < 4; nt++) acc[mt][nt] = (f32x4)0.f;
  const int o0 = w << 5;

  for (int kk = 0; kk < 9; kk++) {
    if (kk == 0) __syncthreads();   // midx ready
    int base = kk * 256 + n;
    int i00 = midx[base], i01 = midx[base + 64], i10 = midx[base + 128], i11 = midx[base + 192];
    float w00 = mwgt[base], w01 = mwgt[base + 64], w10 = mwgt[base + 128], w11 = mwgt[base + 192];
    uint pk[16];
    #pragma unroll 4
    for (int j2 = 0; j2 < 16; j2++) {
      const ushort* xc = xb2 + (size_t)(c0 + 2 * j2) * HWSZ;
      const ushort* xd = xc + HWSZ;
      float v0 = w00 * bff(xc[i00]) + w01 * bff(xc[i01]) + w10 * bff(xc[i10]) + w11 * bff(xc[i11]);
      float v1 = w00 * bff(xd[i00]) + w01 * bff(xd[i01]) + w10 * bff(xd[i10]) + w11 * bff(xd[i11]);
      pk[j2] = pk2(v0, v1);
    }
    __syncthreads();   // prev GEMM done reading vbuf
    #pragma unroll
    for (int k4 = 0; k4 < 4; k4++)
      *(uint4*)&vbuf32[rowu + ((((uint)(c0 >> 1)) + 4u * k4) ^ sw)] =
          make_uint4(pk[k4 * 4], pk[k4 * 4 + 1], pk[k4 * 4 + 2], pk[k4 * 4 + 3]);
    __syncthreads();
    const ushort* wtap = wt2 + (size_t)kk * 65536;
    for (int ks = 0; ks < 8; ks++) {
      short8 af0 = *(const short8*)(wtap + (o0 + fr) * 256 + ks * 32 + fq * 8);
      short8 af1 = *(const short8*)(wtap + (o0 + 16 + fr) * 256 + ks * 32 + fq * 8);
      #pragma unroll
      for (int nt = 0; nt < 4; nt++) {
        int bn = nt * 16 + fr;
        uint idx = (uint)bn * 128u + (((uint)(ks * 16 + fq * 4)) ^ ((uint)(bn & 7) << 2));
        short8 bf = *(const short8*)&vbuf32[idx];
        acc[0][nt] = __builtin_amdgcn_mfma_f32_16x16x32_bf16(af0, bf, acc[0][nt], 0, 0, 0);
        acc[1][nt] = __builtin_amdgcn_mfma_f32_16x16x32_bf16(af1, bf, acc[1][nt], 0, 0, 0);
      }
    }
  }
  // f epilogue
  #pragma unroll
  for (int mt = 0; mt < 2; mt++)
    #pragma unroll
    for (int r = 0; r < 4; r++) {
      int o = o0 + mt * 16 + fq * 4 + r;
      float bo = b_reg[o];
      float* op = out + (size_t)(b * C_ + o) * HWSZ + h * 64;
      #pragma unroll
      for (int nt = 0; nt < 4; nt++) {
        op[nt * 16 + fr] = acc[mt][nt][r] + bo;
        acc[mt][nt][r] = 0.f;
      }
    }

  // ---- Phase 2: mask 1x1 conv (tap 9) ----
  __syncthreads();
  {
    const ushort* xr = xb2 + h * 64 + n;
    uint pk[16];
    #pragma unroll 4
    for (int j = 0; j < 16; j++) {
      uint lo = xr[(size_t)(c0 + 2 * j) * HWSZ];
      uint hi = xr[(size_t)(c0 + 2 * j + 1) * HWSZ];
      pk[j] = lo | (hi << 16);
    }
    #pragma unroll
    for (int k4 = 0; k4 < 4; k4++)
      *(uint4*)&vbuf32[rowu + ((((uint)(c0 >> 1)) + 4u * k4) ^ sw)] =
          make_uint4(pk[k4 * 4], pk[k4 * 4 + 1], pk[k4 * 4 + 2], pk[k4 * 4 + 3]);
  }
  __syncthreads();
  {
    const ushort* wtap = wt2 + (size_t)9 * 65536;
    for (int ks = 0; ks < 8; ks++) {
      short8 af0 = *(const short8*)(wtap + (o0 + fr) * 256 + ks * 32 + fq * 8);
      short8 af1 = *(const short8*)(wtap + (o0 + 16 + fr) * 256 + ks * 32 + fq * 8);
      #pragma unroll
      for (int nt = 0; nt < 4; nt++) {
        int bn = nt * 16 + fr;
        uint idx = (uint)bn * 128u + (((uint)(ks * 16 + fq * 4)) ^ ((uint)(bn & 7) << 2));
        short8 bf = *(const short8*)&vbuf32[idx];
        acc[0][nt] = __builtin_amdgcn_mfma_f32_16x16x32_bf16(af0, bf, acc[0][nt], 0, 0, 0);
        acc[1][nt] = __builtin_amdgcn_mfma_f32_16x16x32_bf16(af1, bf, acc[1][nt], 0, 0, 0);
      }
    }
  }
  ushort* mws = (ushort*)(ws + M_WS);
  #pragma unroll
  for (int mt = 0; mt < 2; mt++)
    #pragma unroll
    for (int r = 0; r < 4; r++) {
      int o = o0 + mt * 16 + fq * 4 + r;
      float bm = b_mask[o];
      ushort* mp = mws + (size_t)(b * C_ + o) * HWSZ + h * 64;
      #pragma unroll
      for (int nt = 0; nt < 4; nt++) {
        float mv = fminf(fmaxf((acc[mt][nt][r] + bm) * (1.f / 6.f) + 0.5f, 0.f), 1.f);
        mp[nt * 16 + fr] = (ushort)bfr(mv);
      }
    }
}

// ---------------- k3: SE global mean ----------------
__global__ __launch_bounds__(256) void k3_reduce(const float* __restrict__ f,
                                                 float* __restrict__ ws) {
  int bc = blockIdx.x;
  int t = threadIdx.x;
  const float* fp = f + (size_t)bc * HWSZ;
  float s = 0.f;
  #pragma unroll
  for (int j = 0; j < 4; j++) {
    float4 v = *(const float4*)&fp[(j * 256 + t) * 4];
    s += v.x + v.y + v.z + v.w;
  }
  #pragma unroll
  for (int off = 32; off > 0; off >>= 1) s += __shfl_down(s, off, 64);
  __shared__ float ps[4];
  if ((t & 63) == 0) ps[t >> 6] = s;
  __syncthreads();
  if (t == 0) ws[SMEAN_WS + bc] = (ps[0] + ps[1] + ps[2] + ps[3]) * (1.f / HWSZ);
}

// ---------------- k4: SE MLP ----------------
__global__ __launch_bounds__(256) void k4_se(
    const float* __restrict__ w_se1, const float* __restrict__ b_se1,
    const float* __restrict__ w_se2, const float* __restrict__ b_se2,
    float* __restrict__ ws) {
  __shared__ float sm[2048];
  __shared__ float s1[512];
  int t = threadIdx.x;
  for (int e = t; e < 2048; e += 256) sm[e] = ws[SMEAN_WS + e];
  __syncthreads();
  for (int e = t; e < 512; e += 256) {
    int b = e >> 6, cr = e & 63;
    float a = b_se1[cr];
    for (int c = 0; c < 256; c++) a += sm[b * 256 + c] * w_se1[cr * 256 + c];
    s1[e] = fmaxf(a, 0.f);
  }
  __syncthreads();
  for (int e = t; e < 2048; e += 256) {
    int b = e >> 8, c = e & 255;
    float a = b_se2[c];
    for (int cr = 0; cr < 64; cr++) a += s1[b * 64 + cr] * w_se2[c * 64 + cr];
    ws[SSCALE_WS + e] = 1.f / (1.f + expf(-a));
  }
}

// ---------------- k5: final combine: out = f*s*m + x ----------------
__global__ __launch_bounds__(256) void k5_final(const float* __restrict__ x,
                                                const float* __restrict__ ws,
                                                float* __restrict__ out) {
  const ushort* mws = (const ushort*)(ws + M_WS);
  int i4 = blockIdx.x * 256 + threadIdx.x;
  const int total = B_ * C_ * HWSZ / 4;
  for (; i4 < total; i4 += gridDim.x * 256) {
    int i = i4 * 4;
    int bc = i >> 12;
    float s = ws[SSCALE_WS + bc];
    float4 f = *(const float4*)&out[i];
    uint2 mu = *(const uint2*)&mws[i];
    float4 xv = *(const float4*)&x[i];
    float4 r;
    r.x = f.x * s * bff((ushort)(mu.x & 0xffffu)) + xv.x;
    r.y = f.y * s * bff((ushort)(mu.x >> 16)) + xv.y;
    r.z = f.z * s * bff((ushort)(mu.y & 0xffffu)) + xv.z;
    r.w = f.w * s * bff((ushort)(mu.y >> 16)) + xv.w;
    *(float4*)&out[i] = r;
  }
}

extern "C" void kernel_launch(void* const* d_in, const int* in_sizes, int n_in,
                              void* d_out, int out_size, void* d_ws, size_t ws_size,
                              hipStream_t stream) {
  const float* x      = (const float*)d_in[0];
  const float* w_off  = (const float*)d_in[1];
  const float* b_off  = (const float*)d_in[2];
  const float* w_mod  = (const float*)d_in[3];
  const float* b_mod  = (const float*)d_in[4];
  const float* w_reg  = (const float*)d_in[5];
  const float* b_reg  = (const float*)d_in[6];
  const float* w_se1  = (const float*)d_in[7];
  const float* b_se1  = (const float*)d_in[8];
  const float* w_se2  = (const float*)d_in[9];
  const float* b_se2  = (const float*)d_in[10];
  const float* w_mask = (const float*)d_in[11];
  const float* b_mask = (const float*)d_in[12];
  float* out = (float*)d_out;
  float* ws  = (float*)d_ws;

  k0_weights<<<dim3(2848), dim3(256), 0, stream>>>(w_reg, w_mask, w_off, w_mod, ws);
  k0b_xcast<<<dim3(4096), dim3(256), 0, stream>>>(x, ws);
  k2_fused<<<dim3(512), dim3(512), 0, stream>>>(b_off, b_mod, b_reg, b_mask, ws, out);
  k3_reduce<<<dim3(2048), dim3(256), 0, stream>>>(out, ws);
  k4_se<<<dim3(1), dim3(256), 0, stream>>>(w_se1, b_se1, w_se2, b_se2, ws);
  k5_final<<<dim3(2048), dim3(256), 0, stream>>>(x, ws, out);
}

// Round 4
// 207.342 us; speedup vs baseline: 4.8624x; 1.6419x over previous
//
#include <hip/hip_runtime.h>
#include <math.h>

#define HWSZ 4096
#define C_ 256
#define B_ 8

// ws layout (float offsets)
#define M_WS      0          // mask bf16: 8*256*4096 ushort = 4194304 floats
#define XB_WS     4194304    // x bf16 NHWC [b][hw][c]: 4194304 floats
#define WT2_WS    8388608    // 10*256*256 ushort = 327680 floats
#define SMEAN_WS  8753152    // 2048 (f channel sums)
#define SSCALE_WS 8755200    // 2048

typedef __attribute__((ext_vector_type(8))) short short8;
typedef __attribute__((ext_vector_type(4))) float f32x4;

__device__ __forceinline__ uint bfr(float a) {  // f32 -> bf16 bits (RNE)
  uint u = __float_as_uint(a);
  return (u + 0x7fffu + ((u >> 16) & 1u)) >> 16;
}
__device__ __forceinline__ uint pk2(float a, float b) { return bfr(a) | (bfr(b) << 16); }
__device__ __forceinline__ float bff(ushort u) { return __uint_as_float((uint)u << 16); }
__device__ __forceinline__ float lo16(uint u) { return __uint_as_float(u << 16); }
__device__ __forceinline__ float hi16(uint u) { return __uint_as_float(u & 0xffff0000u); }

// ---------------- k0: weights -> bf16 (+ zero smean) ----------------
// wt2[kk 0..9][o][c] (kk=9 <- w_mask); wom[s 0..8][o2 0..31][c]
__global__ __launch_bounds__(256) void k0_weights(
    const float* __restrict__ w_reg, const float* __restrict__ w_mask,
    const float* __restrict__ w_off, const float* __restrict__ w_mod,
    float* __restrict__ ws) {
  int i = blockIdx.x * 256 + threadIdx.x;
  const int nwt = 10 * 65536;
  const int total = nwt + 9 * 32 * 256;   // 729088
  if (i >= total) {
    int z = i - total;
    if (z < 2048) ws[SMEAN_WS + z] = 0.f;
    return;
  }
  float v;
  if (i < 9 * 65536) {
    int kk = i >> 16, o = (i >> 8) & 255, c = i & 255;
    v = w_reg[(o * C_ + c) * 9 + kk];
  } else if (i < nwt) {
    v = w_mask[i - 9 * 65536];
  } else {
    int e = i - nwt;
    int s = e >> 13, r = e & 8191;
    int o2 = r >> 8, c = r & 255;
    if (o2 < 18)      v = w_off[(o2 * C_ + c) * 9 + s];
    else if (o2 < 27) v = w_mod[((o2 - 18) * C_ + c) * 9 + s];
    else              v = 0.f;
  }
  ((ushort*)(ws + WT2_WS))[i] = (ushort)bfr(v);
}

// ---------------- k0b: x NCHW f32 -> NHWC bf16 ----------------
__global__ __launch_bounds__(256) void k0b_nhwc(const float* __restrict__ x,
                                                float* __restrict__ ws) {
  __shared__ float tile[64][65];
  int b = blockIdx.x >> 6, hw0 = (blockIdx.x & 63) << 6;
  int t = threadIdx.x;
  uint* xb = (uint*)(ws + XB_WS) + ((size_t)b << 19);
  int rr = t >> 6, cc = t & 63;
  int e = t & 7, hwp = t >> 3;
  for (int cg = 0; cg < 4; cg++) {
    __syncthreads();
    const float* xp = x + ((size_t)(b * 256 + cg * 64 + rr)) * HWSZ + hw0 + cc;
    #pragma unroll
    for (int r0 = 0; r0 < 64; r0 += 4)
      tile[r0 + rr][cc] = xp[(size_t)r0 * HWSZ];
    __syncthreads();
    #pragma unroll
    for (int h2 = 0; h2 < 2; h2++) {
      int hw_l = h2 * 32 + hwp;
      int c2 = e * 8;
      uint4 val;
      val.x = pk2(tile[c2][hw_l], tile[c2 + 1][hw_l]);
      val.y = pk2(tile[c2 + 2][hw_l], tile[c2 + 3][hw_l]);
      val.z = pk2(tile[c2 + 4][hw_l], tile[c2 + 5][hw_l]);
      val.w = pk2(tile[c2 + 6][hw_l], tile[c2 + 7][hw_l]);
      *(uint4*)&xb[(size_t)(hw0 + hw_l) * 128 + cg * 32 + e * 4] = val;
    }
  }
}

// ---------------- k2: fused off/mod conv + deform conv + mask + SE partial sums ----------------
// 512 thr (8 waves) per (b,h) row. Staging: half-wave per position n, 32 lanes x 16B
// coalesced channel reads. vbuf[n][c] bf16, chunk swizzle cl ^ (n&7) (conflict-free).
__global__ __launch_bounds__(512, 4) void k2_fused(
    const float* __restrict__ b_off, const float* __restrict__ b_mod,
    const float* __restrict__ b_reg, const float* __restrict__ b_mask,
    float* __restrict__ ws, float* __restrict__ out) {
  __shared__ uint  vbuf32[64 * 128];   // 32 KB
  __shared__ float offmod[27 * 64];
  __shared__ int   midx[9 * 4 * 64];
  __shared__ float mwgt[9 * 4 * 64];

  int bl = ((blockIdx.x & 7) << 6) | (blockIdx.x >> 3);   // XCD k -> image k
  int b = bl >> 6, h = bl & 63;
  int t = threadIdx.x;
  int lane = t & 63, w = t >> 6;
  const int hwid = (w << 1) | (lane >> 5);   // half-wave id 0..15
  const int cl = lane & 31;                  // channel chunk (8 ch)
  const ushort* xb2 = (const ushort*)(ws + XB_WS) + ((size_t)b << 20);
  const ushort* wt2 = (const ushort*)(ws + WT2_WS);
  const ushort* wom = wt2 + 10 * 65536;
  const int fr = lane & 15, fq = lane >> 4;

  // ---- Phase 0: offset/modulator conv ----
  f32x4 aom = (f32x4)0.f;
  const int m0 = w >> 2, nt0 = w & 3;
  for (int s = 0; s < 9; s++) {
    int row = h + s / 3 - 1;
    uint4 pv[4];
    #pragma unroll
    for (int p = 0; p < 4; p++) {
      int n = p * 16 + hwid;
      int col = n + s % 3 - 1;
      uint4 d = make_uint4(0, 0, 0, 0);
      if (((unsigned)row < 64u) && ((unsigned)col < 64u))
        d = *(const uint4*)(xb2 + ((size_t)(row * 64 + col)) * 256 + cl * 8);
      pv[p] = d;
    }
    __syncthreads();   // prev GEMM done reading vbuf
    #pragma unroll
    for (int p = 0; p < 4; p++) {
      int n = p * 16 + hwid;
      vbuf32[n * 128 + (((uint)(cl * 4)) ^ ((uint)(n & 7) << 2)) + 0] = pv[p].x;
      *(uint4*)&vbuf32[n * 128 + (((uint)(cl * 4)) ^ ((uint)(n & 7) << 2))] = pv[p];
    }
    __syncthreads();
    const ushort* wp = wom + (size_t)s * 8192;
    for (int ks = 0; ks < 8; ks++) {
      short8 af = *(const short8*)(wp + (m0 * 16 + fr) * 256 + ks * 32 + fq * 8);
      int bn = nt0 * 16 + fr;
      uint idx = (uint)bn * 128u + (((uint)(ks * 16 + fq * 4)) ^ ((uint)(bn & 7) << 2));
      short8 bf = *(const short8*)&vbuf32[idx];
      aom = __builtin_amdgcn_mfma_f32_16x16x32_bf16(af, bf, aom, 0, 0, 0);
    }
  }
  __syncthreads();
  #pragma unroll
  for (int r = 0; r < 4; r++) {
    int o = m0 * 16 + fq * 4 + r;
    int nn = nt0 * 16 + fr;
    if (o < 18) {
      offmod[o * 64 + nn] = aom[r] + b_off[o];
    } else if (o < 27) {
      float v = aom[r] + b_mod[o - 18];
      offmod[o * 64 + nn] = 2.f / (1.f + expf(-v));
    }
  }
  __syncthreads();

  // ---- bilinear records for 9 taps ----
  for (int e = t; e < 576; e += 512) {
    int kk = e >> 6, p = e & 63;
    float dy = offmod[(2 * kk) * 64 + p];
    float dx = offmod[(2 * kk + 1) * 64 + p];
    float md = offmod[(18 + kk) * 64 + p];
    float py = (float)(h + kk / 3 - 1) + dy;
    float px = (float)(p + kk % 3 - 1) + dx;
    float fy = floorf(py), fx = floorf(px);
    float ly = py - fy, lx = px - fx;
    int y0 = (int)fy, x0 = (int)fx;
    int y1 = y0 + 1, x1 = x0 + 1;
    float vy0 = ((unsigned)y0 < 64u) ? 1.f : 0.f;
    float vy1 = ((unsigned)y1 < 64u) ? 1.f : 0.f;
    float vx0 = ((unsigned)x0 < 64u) ? 1.f : 0.f;
    float vx1 = ((unsigned)x1 < 64u) ? 1.f : 0.f;
    int cy0 = min(max(y0, 0), 63), cy1 = min(max(y1, 0), 63);
    int cx0 = min(max(x0, 0), 63), cx1 = min(max(x1, 0), 63);
    int base = kk * 256 + p;
    midx[base]       = cy0 * 64 + cx0;
    midx[base + 64]  = cy0 * 64 + cx1;
    midx[base + 128] = cy1 * 64 + cx0;
    midx[base + 192] = cy1 * 64 + cx1;
    mwgt[base]       = (1.f - ly) * (1.f - lx) * md * vy0 * vx0;
    mwgt[base + 64]  = (1.f - ly) * lx * md * vy0 * vx1;
    mwgt[base + 128] = ly * (1.f - lx) * md * vy1 * vx0;
    mwgt[base + 192] = ly * lx * md * vy1 * vx1;
  }
  __syncthreads();

  // ---- Phase 1: 9 deform taps ----
  f32x4 acc[2][4];
  #pragma unroll
  for (int mt = 0; mt < 2; mt++)
    #pragma unroll
    for (int nt = 0; nt < 4; nt++) acc[mt][nt] = (f32x4)0.f;
  const int o0 = w << 5;

  for (int kk = 0; kk < 9; kk++) {
    uint4 pv[4];
    #pragma unroll
    for (int p = 0; p < 4; p++) {
      int n = p * 16 + hwid;
      int base = kk * 256 + n;
      float a0 = 0.f, a1 = 0.f, a2 = 0.f, a3 = 0.f, a4 = 0.f, a5 = 0.f, a6 = 0.f, a7 = 0.f;
      #pragma unroll
      for (int cr = 0; cr < 4; cr++) {
        int gi = midx[base + cr * 64];
        float wv = mwgt[base + cr * 64];
        uint4 d = *(const uint4*)(xb2 + (size_t)gi * 256 + cl * 8);
        a0 = fmaf(wv, lo16(d.x), a0); a1 = fmaf(wv, hi16(d.x), a1);
        a2 = fmaf(wv, lo16(d.y), a2); a3 = fmaf(wv, hi16(d.y), a3);
        a4 = fmaf(wv, lo16(d.z), a4); a5 = fmaf(wv, hi16(d.z), a5);
        a6 = fmaf(wv, lo16(d.w), a6); a7 = fmaf(wv, hi16(d.w), a7);
      }
      pv[p] = make_uint4(pk2(a0, a1), pk2(a2, a3), pk2(a4, a5), pk2(a6, a7));
    }
    __syncthreads();   // prev GEMM done reading vbuf
    #pragma unroll
    for (int p = 0; p < 4; p++) {
      int n = p * 16 + hwid;
      *(uint4*)&vbuf32[n * 128 + (((uint)(cl * 4)) ^ ((uint)(n & 7) << 2))] = pv[p];
    }
    __syncthreads();
    const ushort* wtap = wt2 + (size_t)kk * 65536;
    for (int ks = 0; ks < 8; ks++) {
      short8 af0 = *(const short8*)(wtap + (o0 + fr) * 256 + ks * 32 + fq * 8);
      short8 af1 = *(const short8*)(wtap + (o0 + 16 + fr) * 256 + ks * 32 + fq * 8);
      #pragma unroll
      for (int nt = 0; nt < 4; nt++) {
        int bn = nt * 16 + fr;
        uint idx = (uint)bn * 128u + (((uint)(ks * 16 + fq * 4)) ^ ((uint)(bn & 7) << 2));
        short8 bf = *(const short8*)&vbuf32[idx];
        acc[0][nt] = __builtin_amdgcn_mfma_f32_16x16x32_bf16(af0, bf, acc[0][nt], 0, 0, 0);
        acc[1][nt] = __builtin_amdgcn_mfma_f32_16x16x32_bf16(af1, bf, acc[1][nt], 0, 0, 0);
      }
    }
  }
  // f epilogue + fused SE partial sums
  float* sme = ws + SMEAN_WS + b * 256;
  #pragma unroll
  for (int mt = 0; mt < 2; mt++)
    #pragma unroll
    for (int r = 0; r < 4; r++) {
      int o = o0 + mt * 16 + fq * 4 + r;
      float bo = b_reg[o];
      float* op = out + (size_t)(b * C_ + o) * HWSZ + h * 64;
      float so = 0.f;
      #pragma unroll
      for (int nt = 0; nt < 4; nt++) {
        float fv = acc[mt][nt][r] + bo;
        op[nt * 16 + fr] = fv;
        so += fv;
        acc[mt][nt][r] = 0.f;
      }
      so += __shfl_xor(so, 1);
      so += __shfl_xor(so, 2);
      so += __shfl_xor(so, 4);
      so += __shfl_xor(so, 8);
      if (fr == 0) atomicAdd(&sme[o], so);
    }

  // ---- Phase 2: mask 1x1 conv ----
  {
    uint4 pv[4];
    #pragma unroll
    for (int p = 0; p < 4; p++) {
      int n = p * 16 + hwid;
      pv[p] = *(const uint4*)(xb2 + ((size_t)(h * 64 + n)) * 256 + cl * 8);
    }
    __syncthreads();
    #pragma unroll
    for (int p = 0; p < 4; p++) {
      int n = p * 16 + hwid;
      *(uint4*)&vbuf32[n * 128 + (((uint)(cl * 4)) ^ ((uint)(n & 7) << 2))] = pv[p];
    }
    __syncthreads();
  }
  {
    const ushort* wtap = wt2 + (size_t)9 * 65536;
    for (int ks = 0; ks < 8; ks++) {
      short8 af0 = *(const short8*)(wtap + (o0 + fr) * 256 + ks * 32 + fq * 8);
      short8 af1 = *(const short8*)(wtap + (o0 + 16 + fr) * 256 + ks * 32 + fq * 8);
      #pragma unroll
      for (int nt = 0; nt < 4; nt++) {
        int bn = nt * 16 + fr;
        uint idx = (uint)bn * 128u + (((uint)(ks * 16 + fq * 4)) ^ ((uint)(bn & 7) << 2));
        short8 bf = *(const short8*)&vbuf32[idx];
        acc[0][nt] = __builtin_amdgcn_mfma_f32_16x16x32_bf16(af0, bf, acc[0][nt], 0, 0, 0);
        acc[1][nt] = __builtin_amdgcn_mfma_f32_16x16x32_bf16(af1, bf, acc[1][nt], 0, 0, 0);
      }
    }
  }
  ushort* mws = (ushort*)(ws + M_WS);
  #pragma unroll
  for (int mt = 0; mt < 2; mt++)
    #pragma unroll
    for (int r = 0; r < 4; r++) {
      int o = o0 + mt * 16 + fq * 4 + r;
      float bm = b_mask[o];
      ushort* mp = mws + (size_t)(b * C_ + o) * HWSZ + h * 64;
      #pragma unroll
      for (int nt = 0; nt < 4; nt++) {
        float mv = fminf(fmaxf((acc[mt][nt][r] + bm) * (1.f / 6.f) + 0.5f, 0.f), 1.f);
        mp[nt * 16 + fr] = (ushort)bfr(mv);
      }
    }
}

// ---------------- k4: SE MLP (reads channel SUMS) ----------------
__global__ __launch_bounds__(256) void k4_se(
    const float* __restrict__ w_se1, const float* __restrict__ b_se1,
    const float* __restrict__ w_se2, const float* __restrict__ b_se2,
    float* __restrict__ ws) {
  __shared__ float sm[2048];
  __shared__ float s1[512];
  int t = threadIdx.x;
  for (int e = t; e < 2048; e += 256) sm[e] = ws[SMEAN_WS + e] * (1.f / HWSZ);
  __syncthreads();
  for (int e = t; e < 512; e += 256) {
    int b = e >> 6, cr = e & 63;
    float a = b_se1[cr];
    for (int c = 0; c < 256; c++) a += sm[b * 256 + c] * w_se1[cr * 256 + c];
    s1[e] = fmaxf(a, 0.f);
  }
  __syncthreads();
  for (int e = t; e < 2048; e += 256) {
    int b = e >> 8, c = e & 255;
    float a = b_se2[c];
    for (int cr = 0; cr < 64; cr++) a += s1[b * 64 + cr] * w_se2[c * 64 + cr];
    ws[SSCALE_WS + e] = 1.f / (1.f + expf(-a));
  }
}

// ---------------- k5: final combine: out = f*s*m + x ----------------
__global__ __launch_bounds__(256) void k5_final(const float* __restrict__ x,
                                                const float* __restrict__ ws,
                                                float* __restrict__ out) {
  const ushort* mws = (const ushort*)(ws + M_WS);
  int i4 = blockIdx.x * 256 + threadIdx.x;
  const int total = B_ * C_ * HWSZ / 4;
  for (; i4 < total; i4 += gridDim.x * 256) {
    int i = i4 * 4;
    int bc = i >> 12;
    float s = ws[SSCALE_WS + bc];
    float4 f = *(const float4*)&out[i];
    uint2 mu = *(const uint2*)&mws[i];
    float4 xv = *(const float4*)&x[i];
    float4 r;
    r.x = f.x * s * bff((ushort)(mu.x & 0xffffu)) + xv.x;
    r.y = f.y * s * bff((ushort)(mu.x >> 16)) + xv.y;
    r.z = f.z * s * bff((ushort)(mu.y & 0xffffu)) + xv.z;
    r.w = f.w * s * bff((ushort)(mu.y >> 16)) + xv.w;
    *(float4*)&out[i] = r;
  }
}

extern "C" void kernel_launch(void* const* d_in, const int* in_sizes, int n_in,
                              void* d_out, int out_size, void* d_ws, size_t ws_size,
                              hipStream_t stream) {
  const float* x      = (const float*)d_in[0];
  const float* w_off  = (const float*)d_in[1];
  const float* b_off  = (const float*)d_in[2];
  const float* w_mod  = (const float*)d_in[3];
  const float* b_mod  = (const float*)d_in[4];
  const float* w_reg  = (const float*)d_in[5];
  const float* b_reg  = (const float*)d_in[6];
  const float* w_se1  = (const float*)d_in[7];
  const float* b_se1  = (const float*)d_in[8];
  const float* w_se2  = (const float*)d_in[9];
  const float* b_se2  = (const float*)d_in[10];
  const float* w_mask = (const float*)d_in[11];
  const float* b_mask = (const float*)d_in[12];
  float* out = (float*)d_out;
  float* ws  = (float*)d_ws;

  k0_weights<<<dim3(2856), dim3(256), 0, stream>>>(w_reg, w_mask, w_off, w_mod, ws);
  k0b_nhwc<<<dim3(512), dim3(256), 0, stream>>>(x, ws);
  k2_fused<<<dim3(512), dim3(512), 0, stream>>>(b_off, b_mod, b_reg, b_mask, ws, out);
  k4_se<<<dim3(1), dim3(256), 0, stream>>>(w_se1, b_se1, w_se2, b_se2, ws);
  k5_final<<<dim3(2048), dim3(256), 0, stream>>>(x, ws, out);
}